// Round 5
// baseline (69.539 us; speedup 1.0000x reference)
//
#include <hip/hip_runtime.h>
#include <math.h>

#define B_DIM 256
#define M_DIM 256
#define C_DIM 1024
#define C4    256            // C/4 float4 per row
#define UM_OFF (B_DIM * C_DIM)                       // 262144 floats
#define KL_OFF (UM_OFF + B_DIM * M_DIM * C_DIM)      // 67371008 floats
#define SCALE  0.03125f      // 1/sqrt(1024)

typedef float nfloat4 __attribute__((ext_vector_type(4)));

__device__ __forceinline__ void nt_store4(float4 v, nfloat4* p) {
    nfloat4 n = {v.x, v.y, v.z, v.w};
    __builtin_nontemporal_store(n, p);
}

// ---------------- K1: raw broadcast stream of updated_memory + fused sims ----
// grid (B, 8) x 256 threads (4 waves). Wave w streams 8 rows of um[b] and
// computes sims[b][m] from the same loads. sims stashed in z-row b (scratch).
__global__ __launch_bounds__(256) void tm_stream(const float* __restrict__ x,
                                                 const float* __restrict__ mem,
                                                 float* __restrict__ out) {
    const int b = blockIdx.x;
    const int q = blockIdx.y;          // 0..7
    const int t = threadIdx.x;
    const int lane = t & 63;
    const int wv = t >> 6;             // 0..3

    __shared__ float4 s_x[C4];
    s_x[t] = ((const float4*)(x + (size_t)b * C_DIM))[t];
    __syncthreads();
    const float4 xr0 = s_x[lane];
    const float4 xr1 = s_x[lane + 64];
    const float4 xr2 = s_x[lane + 128];
    const float4 xr3 = s_x[lane + 192];

    const float4* mem4 = (const float4*)mem;
    nfloat4* um4 = (nfloat4*)(out + UM_OFF) + (size_t)b * M_DIM * C4;
    float* simsrow = out + (size_t)b * C_DIM;   // sims[b][m], first 256 floats of z-row b

    const int m0 = (q << 5) | (wv << 3);
    #pragma unroll
    for (int i = 0; i < 8; ++i) {
        const int m = m0 + i;
        const float4* mr = mem4 + (size_t)m * C4;
        float4 a0 = mr[lane];
        float4 a1 = mr[lane + 64];
        float4 a2 = mr[lane + 128];
        float4 a3 = mr[lane + 192];
        float p0 = a0.x*xr0.x + a0.y*xr0.y + a0.z*xr0.z + a0.w*xr0.w;
        float p1 = a1.x*xr1.x + a1.y*xr1.y + a1.z*xr1.z + a1.w*xr1.w;
        float p2 = a2.x*xr2.x + a2.y*xr2.y + a2.z*xr2.z + a2.w*xr2.w;
        float p3 = a3.x*xr3.x + a3.y*xr3.y + a3.z*xr3.z + a3.w*xr3.w;
        float acc = (p0 + p1) + (p2 + p3);
        #pragma unroll
        for (int off = 32; off; off >>= 1) acc += __shfl_xor(acc, off, 64);
        nfloat4* dst = um4 + (size_t)m * C4;
        nt_store4(a0, dst + lane);
        nt_store4(a1, dst + lane + 64);
        nt_store4(a2, dst + lane + 128);
        nt_store4(a3, dst + lane + 192);
        if (lane == 0) simsrow[m] = acc;
    }
}

// ---- block-wide float4 reductions over 8 waves (512 threads) ----
__device__ __forceinline__ float4 bsum4(float4 v, float4* s_w, int lane, int wv) {
    #pragma unroll
    for (int off = 32; off; off >>= 1) {
        v.x += __shfl_xor(v.x, off, 64);
        v.y += __shfl_xor(v.y, off, 64);
        v.z += __shfl_xor(v.z, off, 64);
        v.w += __shfl_xor(v.w, off, 64);
    }
    if (lane == 0) s_w[wv] = v;
    __syncthreads();
    float4 r = s_w[0];
    #pragma unroll
    for (int w = 1; w < 8; ++w) {
        r.x += s_w[w].x; r.y += s_w[w].y; r.z += s_w[w].z; r.w += s_w[w].w;
    }
    __syncthreads();
    return r;
}

__device__ __forceinline__ float4 bmax4(float4 v, float4* s_w, int lane, int wv) {
    #pragma unroll
    for (int off = 32; off; off >>= 1) {
        v.x = fmaxf(v.x, __shfl_xor(v.x, off, 64));
        v.y = fmaxf(v.y, __shfl_xor(v.y, off, 64));
        v.z = fmaxf(v.z, __shfl_xor(v.z, off, 64));
        v.w = fmaxf(v.w, __shfl_xor(v.w, off, 64));
    }
    if (lane == 0) s_w[wv] = v;
    __syncthreads();
    float4 r = s_w[0];
    #pragma unroll
    for (int w = 1; w < 8; ++w) {
        r.x = fmaxf(r.x, s_w[w].x); r.y = fmaxf(r.y, s_w[w].y);
        r.z = fmaxf(r.z, s_w[w].z); r.w = fmaxf(r.w, s_w[w].w);
    }
    __syncthreads();
    return r;
}

// ---------------- K2: per-batch finish. 64 blocks x 512 thr, 4 batches/block.
__global__ __launch_bounds__(512) void tm_finish(const float* __restrict__ x,
                                                 const float* __restrict__ mem,
                                                 float* __restrict__ out) {
    const int g = blockIdx.x;          // 0..63
    const int t = threadIdx.x;         // 0..511
    const int lane = t & 63;
    const int wv = t >> 6;             // 0..7
    const int tc = t & 255;            // column float4 id
    const int h  = t >> 8;             // 0/1 (m-half for z loop)

    __shared__ float4 s_x[4][C4];      // 16 KB
    __shared__ float  s_sims[4][M_DIM];// 4 KB
    __shared__ float4 s_d[4][C4];      // 16 KB  x - mem[idx]
    __shared__ float  s_attn[4][M_DIM];// 4 KB
    __shared__ float4 s_zp[4][C4];     // 16 KB  z partial from half 1
    __shared__ float4 s_w4[8];
    __shared__ float  s_av[8];
    __shared__ int    s_ai[8];
    __shared__ int    s_idx[4];

    const float4* mem4 = (const float4*)mem;

    // ---- stage x rows + sims rows (written by K1 into z-rows) ----
    #pragma unroll
    for (int j = 0; j < 4; ++j) {
        const int b = (g << 2) + j;
        if (h == 0) s_x[j][tc] = ((const float4*)(x + (size_t)b * C_DIM))[tc];
        else        s_sims[j][tc] = out[(size_t)b * C_DIM + tc];
    }
    __syncthreads();

    // ---- n2 = ||x||^2 per batch ----
    float4 pv = make_float4(0.f, 0.f, 0.f, 0.f);
    if (h == 0) {
        float4 x0 = s_x[0][tc], x1 = s_x[1][tc], x2 = s_x[2][tc], x3 = s_x[3][tc];
        pv.x = x0.x*x0.x + x0.y*x0.y + x0.z*x0.z + x0.w*x0.w;
        pv.y = x1.x*x1.x + x1.y*x1.y + x1.z*x1.z + x1.w*x1.w;
        pv.z = x2.x*x2.x + x2.y*x2.y + x2.z*x2.z + x2.w*x2.w;
        pv.w = x3.x*x3.x + x3.y*x3.y + x3.z*x3.z + x3.w*x3.w;
    }
    float4 n2v = bsum4(pv, s_w4, lane, wv);
    const float n2_[4] = {n2v.x, n2v.y, n2v.z, n2v.w};

    // ---- argmax per batch (first-max tie-break, like np.argmax) ----
    #pragma unroll
    for (int j = 0; j < 4; ++j) {
        float av = -INFINITY; int ai = 0x7fffffff;
        if (h == 0) { av = s_sims[j][tc]; ai = tc; }
        #pragma unroll
        for (int off = 32; off; off >>= 1) {
            float ov = __shfl_xor(av, off, 64);
            int   oi = __shfl_xor(ai, off, 64);
            if (ov > av || (ov == av && oi < ai)) { av = ov; ai = oi; }
        }
        if (lane == 0) { s_av[wv] = av; s_ai[wv] = ai; }
        __syncthreads();
        if (t == 0) {
            float bv = s_av[0]; int bi = s_ai[0];
            #pragma unroll
            for (int w = 1; w < 8; ++w) {
                float v2 = s_av[w]; int i2 = s_ai[w];
                if (v2 > bv || (v2 == bv && i2 < bi)) { bv = v2; bi = i2; }
            }
            s_idx[j] = bi;
        }
        __syncthreads();
    }

    // ---- blend rows (rewrite um[b][idx]), d = x - sel, dw = ||d||^2 ----
    float4 dwp = make_float4(0.f, 0.f, 0.f, 0.f);
    #pragma unroll
    for (int j = 0; j < 4; ++j) {
        const int b = (g << 2) + j;
        const int idx = s_idx[j];
        if (h == 0) {
            float4 sl = mem4[(size_t)idx * C4 + tc];
            float4 xv = s_x[j][tc];
            float4 d = make_float4(xv.x - sl.x, xv.y - sl.y, xv.z - sl.z, xv.w - sl.w);
            s_d[j][tc] = d;
            float dd = d.x*d.x + d.y*d.y + d.z*d.z + d.w*d.w;
            if      (j == 0) dwp.x = dd;
            else if (j == 1) dwp.y = dd;
            else if (j == 2) dwp.z = dd;
            else             dwp.w = dd;
            float4 bl = make_float4(0.9f*sl.x + 0.1f*xv.x, 0.9f*sl.y + 0.1f*xv.y,
                                    0.9f*sl.z + 0.1f*xv.z, 0.9f*sl.w + 0.1f*xv.w);
            nt_store4(bl, (nfloat4*)(out + UM_OFF) + ((size_t)b * M_DIM + idx) * C4 + tc);
        }
    }
    float4 dwv = bsum4(dwp, s_w4, lane, wv);
    const float dw_[4] = {dwv.x, dwv.y, dwv.z, dwv.w};

    // ---- scores + softmax ----
    float4 scv = make_float4(-INFINITY, -INFINITY, -INFINITY, -INFINITY);
    if (h == 0) {
        #pragma unroll
        for (int j = 0; j < 4; ++j) {
            const int idx = s_idx[j];
            float sc = (tc == idx) ? (0.9f * s_sims[j][idx] + 0.1f * n2_[j]) * SCALE
                                   : s_sims[j][tc] * SCALE;
            if      (j == 0) scv.x = sc;
            else if (j == 1) scv.y = sc;
            else if (j == 2) scv.z = sc;
            else             scv.w = sc;
        }
    }
    float4 mxv = bmax4(scv, s_w4, lane, wv);
    float4 ev = make_float4(0.f, 0.f, 0.f, 0.f);
    if (h == 0) {
        ev.x = expf(scv.x - mxv.x);
        ev.y = expf(scv.y - mxv.y);
        ev.z = expf(scv.z - mxv.z);
        ev.w = expf(scv.w - mxv.w);
    }
    float4 esv = bsum4(ev, s_w4, lane, wv);
    if (h == 0) {
        s_attn[0][tc] = ev.x / esv.x;
        s_attn[1][tc] = ev.y / esv.y;
        s_attn[2][tc] = ev.z / esv.z;
        s_attn[3][tc] = ev.w / esv.w;
    }
    __syncthreads();

    // ---- z = attn @ mem, m-range split across halves ----
    float4 z0 = make_float4(0.f,0.f,0.f,0.f), z1 = z0, z2 = z0, z3 = z0;
    #pragma unroll 4
    for (int i = 0; i < 128; ++i) {
        const int m = (h << 7) + i;
        float4 v = mem4[(size_t)m * C4 + tc];
        const float a0 = s_attn[0][m], a1 = s_attn[1][m];
        const float a2 = s_attn[2][m], a3 = s_attn[3][m];
        z0.x = fmaf(a0, v.x, z0.x); z0.y = fmaf(a0, v.y, z0.y);
        z0.z = fmaf(a0, v.z, z0.z); z0.w = fmaf(a0, v.w, z0.w);
        z1.x = fmaf(a1, v.x, z1.x); z1.y = fmaf(a1, v.y, z1.y);
        z1.z = fmaf(a1, v.z, z1.z); z1.w = fmaf(a1, v.w, z1.w);
        z2.x = fmaf(a2, v.x, z2.x); z2.y = fmaf(a2, v.y, z2.y);
        z2.z = fmaf(a2, v.z, z2.z); z2.w = fmaf(a2, v.w, z2.w);
        z3.x = fmaf(a3, v.x, z3.x); z3.y = fmaf(a3, v.y, z3.y);
        z3.z = fmaf(a3, v.z, z3.z); z3.w = fmaf(a3, v.w, z3.w);
    }
    if (h == 1) { s_zp[0][tc] = z0; s_zp[1][tc] = z1; s_zp[2][tc] = z2; s_zp[3][tc] = z3; }
    __syncthreads();

    float4 drp = make_float4(0.f, 0.f, 0.f, 0.f);
    if (h == 0) {
        float4 o0 = s_zp[0][tc], o1 = s_zp[1][tc], o2 = s_zp[2][tc], o3 = s_zp[3][tc];
        z0.x += o0.x; z0.y += o0.y; z0.z += o0.z; z0.w += o0.w;
        z1.x += o1.x; z1.y += o1.y; z1.z += o1.z; z1.w += o1.w;
        z2.x += o2.x; z2.y += o2.y; z2.z += o2.z; z2.w += o2.w;
        z3.x += o3.x; z3.y += o3.y; z3.z += o3.z; z3.w += o3.w;
        const float ax0 = s_attn[0][s_idx[0]] * 0.1f;
        const float ax1 = s_attn[1][s_idx[1]] * 0.1f;
        const float ax2 = s_attn[2][s_idx[2]] * 0.1f;
        const float ax3 = s_attn[3][s_idx[3]] * 0.1f;
        float4 d0 = s_d[0][tc], d1 = s_d[1][tc], d2 = s_d[2][tc], d3 = s_d[3][tc];
        z0.x = fmaf(ax0, d0.x, z0.x); z0.y = fmaf(ax0, d0.y, z0.y);
        z0.z = fmaf(ax0, d0.z, z0.z); z0.w = fmaf(ax0, d0.w, z0.w);
        z1.x = fmaf(ax1, d1.x, z1.x); z1.y = fmaf(ax1, d1.y, z1.y);
        z1.z = fmaf(ax1, d1.z, z1.z); z1.w = fmaf(ax1, d1.w, z1.w);
        z2.x = fmaf(ax2, d2.x, z2.x); z2.y = fmaf(ax2, d2.y, z2.y);
        z2.z = fmaf(ax2, d2.z, z2.z); z2.w = fmaf(ax2, d2.w, z2.w);
        z3.x = fmaf(ax3, d3.x, z3.x); z3.y = fmaf(ax3, d3.y, z3.y);
        z3.z = fmaf(ax3, d3.z, z3.z); z3.w = fmaf(ax3, d3.w, z3.w);
        float4 x0 = s_x[0][tc], x1 = s_x[1][tc], x2 = s_x[2][tc], x3 = s_x[3][tc];
        float e0x = z0.x-x0.x, e0y = z0.y-x0.y, e0z = z0.z-x0.z, e0w = z0.w-x0.w;
        float e1x = z1.x-x1.x, e1y = z1.y-x1.y, e1z = z1.z-x1.z, e1w = z1.w-x1.w;
        float e2x = z2.x-x2.x, e2y = z2.y-x2.y, e2z = z2.z-x2.z, e2w = z2.w-x2.w;
        float e3x = z3.x-x3.x, e3y = z3.y-x3.y, e3z = z3.z-x3.z, e3w = z3.w-x3.w;
        drp.x = e0x*e0x + e0y*e0y + e0z*e0z + e0w*e0w;
        drp.y = e1x*e1x + e1y*e1y + e1z*e1z + e1w*e1w;
        drp.z = e2x*e2x + e2y*e2y + e2z*e2z + e2w*e2w;
        drp.w = e3x*e3x + e3y*e3y + e3z*e3z + e3w*e3w;
        float4* zout = (float4*)out;
        zout[((size_t)((g << 2) + 0)) * C4 + tc] = z0;   // overwrites own sims scratch
        zout[((size_t)((g << 2) + 1)) * C4 + tc] = z1;
        zout[((size_t)((g << 2) + 2)) * C4 + tc] = z2;
        zout[((size_t)((g << 2) + 3)) * C4 + tc] = z3;
    }
    float4 drv = bsum4(drp, s_w4, lane, wv);
    if (t == 0) {
        out[KL_OFF + (g << 2) + 0] = 0.5f * (dw_[0] + drv.x);
        out[KL_OFF + (g << 2) + 1] = 0.5f * (dw_[1] + drv.y);
        out[KL_OFF + (g << 2) + 2] = 0.5f * (dw_[2] + drv.z);
        out[KL_OFF + (g << 2) + 3] = 0.5f * (dw_[3] + drv.w);
    }
}

extern "C" void kernel_launch(void* const* d_in, const int* in_sizes, int n_in,
                              void* d_out, int out_size, void* d_ws, size_t ws_size,
                              hipStream_t stream) {
    const float* x   = (const float*)d_in[0];   // input_encoded [B, C]
    const float* mem = (const float*)d_in[1];   // memory_mean  [M, C]
    float* out = (float*)d_out;

    tm_stream<<<dim3(B_DIM, 8), dim3(256), 0, stream>>>(x, mem, out);
    tm_finish<<<dim3(64), dim3(512), 0, stream>>>(x, mem, out);
}